// Round 3
// baseline (328.155 us; speedup 1.0000x reference)
//
#include <hip/hip_runtime.h>
#include <hip/hip_bf16.h>

#define BN_EPS 1e-5f
#define NBMAX 512      // max buckets (N/256)
#define CHUNK 4096     // edges per binning block
#define CAP   5120     // fixed per-bucket capacity (mean 4096 + 16 sigma)
#define PCAP  7168     // padded per-bucket adj capacity (CAP + 256*7 = 6912 <= 7168, mult of 8)

typedef __hip_bfloat16 bf16;
typedef __attribute__((ext_vector_type(8))) short short8;
typedef __attribute__((ext_vector_type(4))) float f32x4;

__device__ __forceinline__ float b2f(bf16 v) { return __bfloat162float(v); }
__device__ __forceinline__ bf16 f2b(float v) { return __float2bfloat16(v); }
__device__ __forceinline__ float bl(unsigned u) { return __uint_as_float(u << 16); }
__device__ __forceinline__ float bh(unsigned u) { return __uint_as_float(u & 0xffff0000u); }
__device__ __forceinline__ unsigned pack2(float x, float y) {
    union { bf16 b[2]; unsigned u; } p;
    p.b[0] = f2b(x); p.b[1] = f2b(y);
    return p.u;
}
__device__ __forceinline__ float bs2f(short s) {
    return __uint_as_float(((unsigned)(unsigned short)s) << 16);
}
__device__ __forceinline__ short f2bs(float v) {
    bf16 b = f2b(v);
    return *reinterpret_cast<short*>(&b);
}

// bn scale/shift from global S/Q sums: sc = g*rsqrt(Q/N-(S/N)^2+eps), sh = be-m*sc
__device__ __forceinline__ void bn_sc_sh(
    const float* __restrict__ gs, const float* __restrict__ g,
    const float* __restrict__ be, float invN, int f, float* sc, float* sh)
{
    float S = gs[f], Q = gs[64 + f];
    float m = S * invN;
    float v = Q * invN - m * m;
    float s = g[f] * rsqrtf(v + BN_EPS);
    *sc = s;
    *sh = be[f] - m * s;
}

// ============ init bcur + stats + cast x -> bf16; pad rows: xb[N]=0, zb[N]=NaN ====
__global__ __launch_bounds__(256) void initcast_k(
    const float* __restrict__ in, bf16* __restrict__ xb, bf16* __restrict__ zb,
    int n4, int total4, int* __restrict__ bcur, int NB, float* __restrict__ gs)
{
    if (blockIdx.x == 0) {
        for (int i = threadIdx.x; i < NB; i += 256) bcur[i] = i * CAP;
        for (int i = threadIdx.x; i < 512; i += 256) gs[i] = 0.f;   // 4 stat slots
    }
    int i = blockIdx.x * 256 + threadIdx.x;
    if (i >= total4) return;
    if (i < n4) {
        float4 v = ((const float4*)in)[i];
        union { ushort4 u; bf16 b[4]; } p;
        p.b[0] = f2b(v.x); p.b[1] = f2b(v.y); p.b[2] = f2b(v.z); p.b[3] = f2b(v.w);
        ((ushort4*)xb)[i] = p.u;
    } else {
        ushort4 z; z.x = 0; z.y = 0; z.z = 0; z.w = 0;
        ((ushort4*)xb)[i] = z;   // zero pad row N of xb
    }
}

// ============ binscatter: group edges by bucket in LDS, write coalesced runs ====
__global__ __launch_bounds__(256) void binscatter_k(
    const int* __restrict__ src, const int* __restrict__ dst,
    int* __restrict__ bcur, int* __restrict__ tmp, int E, int NB)
{
    __shared__ int hist[NBMAX];
    __shared__ int loff[NBMAX];
    __shared__ int gb[NBMAX];
    __shared__ int lcur[NBMAX];
    __shared__ int staged[CHUNK];
    __shared__ unsigned short sb[CHUNK];
    __shared__ int ssc[256];
    const int t = threadIdx.x;
    for (int i = t; i < NB; i += 256) { hist[i] = 0; lcur[i] = 0; }
    __syncthreads();
    const int base = blockIdx.x * CHUNK;
    const int lim = min(CHUNK, E - base);
    int myb[16], myw[16];
    int cnt = 0;
    for (int i = t; i < lim; i += 256) {
        int d = dst[base + i];
        int s_ = src[base + i];
        int b = d >> 8;
        myb[cnt] = b;
        myw[cnt] = (s_ << 8) | (d & 255);
        cnt++;
        atomicAdd(&hist[b], 1);
    }
    __syncthreads();
    int v0 = (2 * t     < NB) ? hist[2 * t]     : 0;
    int v1 = (2 * t + 1 < NB) ? hist[2 * t + 1] : 0;
    ssc[t] = v0 + v1;
    __syncthreads();
    for (int off = 1; off < 256; off <<= 1) {
        int a = (t >= off) ? ssc[t - off] : 0;
        __syncthreads();
        ssc[t] += a;
        __syncthreads();
    }
    int excl = ssc[t] - (v0 + v1);
    if (2 * t < NB)     loff[2 * t] = excl;
    if (2 * t + 1 < NB) loff[2 * t + 1] = excl + v0;
    __syncthreads();
    for (int b = t; b < NB; b += 256)
        if (hist[b] > 0) gb[b] = atomicAdd(&bcur[b], hist[b]);
    for (int i = 0; i < cnt; i++) {
        int b = myb[i];
        int p = loff[b] + atomicAdd(&lcur[b], 1);
        staged[p] = myw[i];
        sb[p] = (unsigned short)b;
    }
    __syncthreads();
    for (int i = t; i < lim; i += 256) {
        int b = sb[i];
        tmp[gb[b] + (i - loff[b])] = staged[i];
    }
}

// ============ csr: per bucket counting sort -> 8-padded rows (pad idx = N) ======
__global__ __launch_bounds__(256) void csr_k(
    const int* __restrict__ bcur, const int* __restrict__ tmp,
    int* __restrict__ rowptr, int* __restrict__ rowend,
    int* __restrict__ adj, int N)
{
    __shared__ int hist[256], pfx[256], cur[256], ssc[256];
    __shared__ int sadj[PCAP];
    const int b = blockIdx.x, t = threadIdx.x;
    const int lo = b * CAP;          // tmp base (unpadded)
    const int plo = b * PCAP;        // adj base (padded)
    const int cnt = min(bcur[b] - lo, CAP);
    hist[t] = 0; cur[t] = 0;
    __syncthreads();
    for (int i = t; i < cnt; i += 256)
        atomicAdd(&hist[tmp[lo + i] & 255], 1);
    __syncthreads();
    const int v = hist[t];
    const int pv = (v + 7) & ~7;     // pad each row to multiple of 8
    ssc[t] = pv;
    __syncthreads();
    for (int off = 1; off < 256; off <<= 1) {
        int a = (t >= off) ? ssc[t - off] : 0;
        __syncthreads();
        ssc[t] += a;
        __syncthreads();
    }
    const int myp = ssc[t] - pv;
    pfx[t] = myp;
    const int node = b * 256 + t;
    if (node < N) {
        rowptr[node] = plo + myp;
        rowend[node] = plo + myp + pv;
    }
    __syncthreads();
    const int pcnt = ssc[255];       // <= CAP + 256*7 = 6912 <= PCAP always
    for (int i = t; i < cnt; i += 256) {
        int w = tmp[lo + i];
        int d = w & 255;
        int p = pfx[d] + atomicAdd(&cur[d], 1);
        sadj[p] = w >> 8;
    }
    __syncthreads();
    for (int i = v; i < pv; i++) sadj[myp + i] = N;   // pad -> zero row
    __syncthreads();
    for (int i = t; i < pcnt; i += 256) adj[plo + i] = sadj[i];
}

// ========== aggregation: z[n] = act(h[n]) + sum_m act(h[m]); rows 8-padded =======
// MODE 0: act = id (pads gather zero row N, harmless).
// MODE 1: act = relu(v*sc+sh) with sc/sh derived from gstat; pads masked to 0.
// 16 lanes per node, dwordx2 loads: one gather instr = full 128B row per group.
template<int MODE>
__global__ __launch_bounds__(256, 4) void aggregate_k(
    const bf16* __restrict__ h, const int* __restrict__ rowptr,
    const int* __restrict__ rowend, const int* __restrict__ adj,
    bf16* __restrict__ z, int N,
    const float* __restrict__ gs, const float* __restrict__ bng,
    const float* __restrict__ bnb, float invN)
{
    __shared__ float sSc[64], sSh[64];
    const int tid = threadIdx.x;
    if (MODE == 1) {
        if (tid < 64) bn_sc_sh(gs, bng, bnb, invN, tid, &sSc[tid], &sSh[tid]);
        __syncthreads();
    }
    const int lane16 = tid & 15;
    const int n = blockIdx.x * 16 + (tid >> 4);
    if (n >= N) return;
    float sc0 = 0.f, sc1 = 0.f, sc2 = 0.f, sc3 = 0.f;
    float sh0 = 0.f, sh1 = 0.f, sh2 = 0.f, sh3 = 0.f;
    if (MODE == 1) {
        const int f0 = lane16 * 4;
        sc0 = sSc[f0];     sh0 = sSh[f0];
        sc1 = sSc[f0 + 1]; sh1 = sSh[f0 + 1];
        sc2 = sSc[f0 + 2]; sh2 = sSh[f0 + 2];
        sc3 = sSc[f0 + 3]; sh3 = sSh[f0 + 3];
    }
    const char* hb_ = (const char*)h;   // row stride 128B
    const int b = rowptr[n], e = rowend[n];

    uint2 u = *(const uint2*)(hb_ + ((size_t)n << 7) + (lane16 << 3));
    float s0 = bl(u.x), s1 = bh(u.x), s2 = bl(u.y), s3 = bh(u.y);
    if (MODE == 1) {
        s0 = fmaxf(fmaf(s0, sc0, sh0), 0.f);
        s1 = fmaxf(fmaf(s1, sc1, sh1), 0.f);
        s2 = fmaxf(fmaf(s2, sc2, sh2), 0.f);
        s3 = fmaxf(fmaf(s3, sc3, sh3), 0.f);
    }

    int m[8], mc[8];
    if (b < e) {
        #pragma unroll
        for (int k = 0; k < 8; k++) m[k] = adj[b + k];
    }
    for (int i = b; i < e; ) {
        #pragma unroll
        for (int k = 0; k < 8; k++) mc[k] = m[k];
        uint2 w[8];
        #pragma unroll
        for (int k = 0; k < 8; k++)
            w[k] = *(const uint2*)(hb_ + (((size_t)(unsigned)mc[k]) << 7) + (lane16 << 3));
        const int inext = i + 8;
        if (inext < e) {
            #pragma unroll
            for (int k = 0; k < 8; k++) m[k] = adj[inext + k];
        }
        #pragma unroll
        for (int k = 0; k < 8; k++) {
            float p0 = bl(w[k].x), p1 = bh(w[k].x);
            float p2 = bl(w[k].y), p3 = bh(w[k].y);
            if (MODE == 1) {
                const bool real = mc[k] < N;   // pad rows contribute exactly 0
                p0 = real ? fmaxf(fmaf(p0, sc0, sh0), 0.f) : 0.f;
                p1 = real ? fmaxf(fmaf(p1, sc1, sh1), 0.f) : 0.f;
                p2 = real ? fmaxf(fmaf(p2, sc2, sh2), 0.f) : 0.f;
                p3 = real ? fmaxf(fmaf(p3, sc3, sh3), 0.f) : 0.f;
            }
            s0 += p0; s1 += p1; s2 += p2; s3 += p3;
        }
        i = inext;
    }
    uint2 o;
    o.x = pack2(s0, s1);
    o.y = pack2(s2, s3);
    *(uint2*)((char*)z + ((size_t)n << 7) + (lane16 << 3)) = o;
}

// ---------------- MFMA GEMM (bf16 in/out, f32 acc) ----------------
// C[N x 64] = act(A) @ W + bias.  MODE 0: act = id;  MODE 1: act = relu(A*sc+sh)
// with sc/sh computed in-prologue from gstat_in (producer gemm's atomic sums).
// Per-block S/Q stats atomically accumulated into gstat_out (zeroed by initcast).
template<int MODE>
__global__ __launch_bounds__(256) void gemm64_k(
    const bf16* __restrict__ A,
    const float* __restrict__ gstat_in, const float* __restrict__ bng,
    const float* __restrict__ bnb, float invN,
    const float* __restrict__ W, const float* __restrict__ bias,
    bf16* __restrict__ out, float* __restrict__ gstat_out, int nrows)
{
    __shared__ bf16 sWt[64][72];     // transposed W (n-major)
    __shared__ bf16 sC[128][68];     // C tile; 136B rows: 8B-aligned, 2-way bank alias
    __shared__ float sSc[64], sSh[64], sB[64];
    __shared__ float sredS[64][17], sredQ[64][17];
    const int tid = threadIdx.x;

    if (tid < 64) {
        sB[tid] = bias[tid];
        if (MODE == 1) bn_sc_sh(gstat_in, bng, bnb, invN, tid, &sSc[tid], &sSh[tid]);
    }
    for (int i = tid; i < 4096; i += 256) {
        int k = i >> 6, n = i & 63;
        sWt[n][k] = f2b(W[i]);
    }
    __syncthreads();

    const int wave = tid >> 6, lane = tid & 63;
    const int quad = lane >> 4, l16 = lane & 15;
    const int row0 = blockIdx.x * 128 + wave * 32;

    short8 a[2][2];
    #pragma unroll
    for (int rt = 0; rt < 2; rt++) {
        int r = row0 + rt * 16 + l16;
        int rr = min(r, nrows - 1);
        const bf16* arow = A + (size_t)rr * 64;
        a[rt][0] = *(const short8*)(arow + quad * 8);
        a[rt][1] = *(const short8*)(arow + 32 + quad * 8);
        if (MODE == 1) {
            #pragma unroll
            for (int j = 0; j < 8; j++) {
                int f0 = quad * 8 + j;
                a[rt][0][j] = f2bs(fmaxf(fmaf(bs2f(a[rt][0][j]), sSc[f0], sSh[f0]), 0.f));
                int f1 = 32 + f0;
                a[rt][1][j] = f2bs(fmaxf(fmaf(bs2f(a[rt][1][j]), sSc[f1], sSh[f1]), 0.f));
            }
        }
    }

    float psS[4], psQ[4];
    #pragma unroll
    for (int t = 0; t < 4; t++) { psS[t] = 0.f; psQ[t] = 0.f; }

    #pragma unroll
    for (int t = 0; t < 4; t++) {
        const int n = t * 16 + l16;
        short8 b0 = *(const short8*)&sWt[n][quad * 8];
        short8 b1 = *(const short8*)&sWt[n][32 + quad * 8];
        const float bn_ = sB[n];
        #pragma unroll
        for (int rt = 0; rt < 2; rt++) {
            f32x4 acc = {0.f, 0.f, 0.f, 0.f};
            acc = __builtin_amdgcn_mfma_f32_16x16x32_bf16(a[rt][0], b0, acc, 0, 0, 0);
            acc = __builtin_amdgcn_mfma_f32_16x16x32_bf16(a[rt][1], b1, acc, 0, 0, 0);
            #pragma unroll
            for (int reg = 0; reg < 4; reg++) {
                const int lr = wave * 32 + rt * 16 + quad * 4 + reg;  // local row
                float v = acc[reg] + bn_;
                sC[lr][n] = f2b(v);
                if (row0 + rt * 16 + quad * 4 + reg < nrows) {
                    psS[t] += v;
                    psQ[t] = fmaf(v, v, psQ[t]);
                }
            }
        }
    }

    #pragma unroll
    for (int t = 0; t < 4; t++) {
        sredS[t * 16 + l16][wave * 4 + quad] = psS[t];
        sredQ[t * 16 + l16][wave * 4 + quad] = psQ[t];
    }
    __syncthreads();

    // coalesced C-tile writeout: 2048 ushort4 chunks (128 rows x 16)
    const int gbase = blockIdx.x * 128;
    #pragma unroll
    for (int it = 0; it < 8; it++) {
        int idx = it * 256 + tid;
        int r = idx >> 4, c4 = idx & 15;
        if (gbase + r < nrows) {
            ushort4 v = *(const ushort4*)&sC[r][c4 * 4];
            *(ushort4*)(out + (size_t)(gbase + r) * 64 + c4 * 4) = v;
        }
    }

    if (tid < 128) {
        const int c = tid & 63;
        const float* p = (tid < 64) ? &sredS[c][0] : &sredQ[c][0];
        float s = 0.f;
        #pragma unroll
        for (int i = 0; i < 16; i++) s += p[i];
        atomicAdd(&gstat_out[(tid < 64) ? c : 64 + c], s);
    }
}

// ---------------- pooled readout; h1/h2 affine+relu applied on the fly ----------
// 16 groups x 16 lanes; uint2 loads (8B/lane), 4 features per lane.
__global__ __launch_bounds__(256) void pool_readout_k(
    const bf16* __restrict__ xb, const bf16* __restrict__ y0,
    const bf16* __restrict__ y1, const int* __restrict__ batch,
    const float* __restrict__ gsA, const float* __restrict__ gA, const float* __restrict__ beA,
    const float* __restrict__ gsB, const float* __restrict__ gB, const float* __restrict__ beB,
    float invN,
    const float* __restrict__ w0, const float* __restrict__ b0,
    const float* __restrict__ w1, const float* __restrict__ b1,
    const float* __restrict__ w2, const float* __restrict__ b2,
    float* __restrict__ out, int Nn)
{
    __shared__ float sA[2][64], sB2[2][64];
    __shared__ float p[3][16][64];
    __shared__ float q[3][64];
    const int tid = threadIdx.x;
    if (tid < 64) {
        bn_sc_sh(gsA, gA, beA, invN, tid, &sA[0][tid], &sA[1][tid]);
    } else if (tid < 128) {
        int f = tid - 64;
        bn_sc_sh(gsB, gB, beB, invN, f, &sB2[0][f], &sB2[1][f]);
    }
    __syncthreads();

    const int g = blockIdx.x;
    int lo = 0, hi = Nn;
    while (lo < hi) { int mid = (lo + hi) >> 1; if (batch[mid] < g) lo = mid + 1; else hi = mid; }
    const int start = lo;
    hi = Nn;
    while (lo < hi) { int mid = (lo + hi) >> 1; if (batch[mid] <= g) lo = mid + 1; else hi = mid; }
    const int end = lo;

    const int l16 = tid & 15, grp = tid >> 4;
    const int f0 = l16 * 4;
    const float scA0 = sA[0][f0],     shA0 = sA[1][f0];
    const float scA1 = sA[0][f0 + 1], shA1 = sA[1][f0 + 1];
    const float scA2 = sA[0][f0 + 2], shA2 = sA[1][f0 + 2];
    const float scA3 = sA[0][f0 + 3], shA3 = sA[1][f0 + 3];
    const float scB0 = sB2[0][f0],     shB0 = sB2[1][f0];
    const float scB1 = sB2[0][f0 + 1], shB1 = sB2[1][f0 + 1];
    const float scB2 = sB2[0][f0 + 2], shB2 = sB2[1][f0 + 2];
    const float scB3 = sB2[0][f0 + 3], shB3 = sB2[1][f0 + 3];

    float a0 = 0.f, a1 = 0.f, a2 = 0.f, a3 = 0.f;
    float h0 = 0.f, h1 = 0.f, h2 = 0.f, h3 = 0.f;
    float c0 = 0.f, c1 = 0.f, c2 = 0.f, c3 = 0.f;
    for (int i = start + grp; i < end; i += 16) {
        const size_t ro = (size_t)i * 16 + l16;
        uint2 ux = ((const uint2*)xb)[ro];
        uint2 u0 = ((const uint2*)y0)[ro];
        uint2 u1 = ((const uint2*)y1)[ro];
        a0 += bl(ux.x); a1 += bh(ux.x); a2 += bl(ux.y); a3 += bh(ux.y);
        h0 += fmaxf(fmaf(bl(u0.x), scA0, shA0), 0.f);
        h1 += fmaxf(fmaf(bh(u0.x), scA1, shA1), 0.f);
        h2 += fmaxf(fmaf(bl(u0.y), scA2, shA2), 0.f);
        h3 += fmaxf(fmaf(bh(u0.y), scA3, shA3), 0.f);
        c0 += fmaxf(fmaf(bl(u1.x), scB0, shB0), 0.f);
        c1 += fmaxf(fmaf(bh(u1.x), scB1, shB1), 0.f);
        c2 += fmaxf(fmaf(bl(u1.y), scB2, shB2), 0.f);
        c3 += fmaxf(fmaf(bh(u1.y), scB3, shB3), 0.f);
    }
    p[0][grp][f0] = a0; p[0][grp][f0 + 1] = a1; p[0][grp][f0 + 2] = a2; p[0][grp][f0 + 3] = a3;
    p[1][grp][f0] = h0; p[1][grp][f0 + 1] = h1; p[1][grp][f0 + 2] = h2; p[1][grp][f0 + 3] = h3;
    p[2][grp][f0] = c0; p[2][grp][f0 + 1] = c1; p[2][grp][f0 + 2] = c2; p[2][grp][f0 + 3] = c3;
    __syncthreads();

    if (tid < 192) {
        const int arr = tid >> 6, f = tid & 63;
        float s = 0.f;
        #pragma unroll
        for (int i = 0; i < 16; i++) s += p[arr][i][f];
        q[arr][f] = s;
    }
    __syncthreads();

    if (tid < 10) {
        const int c = tid;
        float acc = b0[c] + b1[c] + b2[c];
        for (int k = 0; k < 64; k++) {
            acc = fmaf(q[0][k], w0[k * 10 + c], acc);
            acc = fmaf(q[1][k], w1[k * 10 + c], acc);
            acc = fmaf(q[2][k], w2[k * 10 + c], acc);
        }
        out[(size_t)g * 10 + c] = acc;
    }
}

extern "C" void kernel_launch(void* const* d_in, const int* in_sizes, int n_in,
                              void* d_out, int out_size, void* d_ws, size_t ws_size,
                              hipStream_t stream)
{
    const float* x     = (const float*)d_in[0];
    const int*   edge  = (const int*)d_in[1];
    const int*   batch = (const int*)d_in[2];
    const int N = in_sizes[0] / 64;
    const int E = in_sizes[1] / 2;
    const int G = out_size / 10;
    const int* src = edge;
    const int* dst = edge + E;
    const int NB = (N + 255) / 256;

    const float* c_w1[2]  = {(const float*)d_in[3],  (const float*)d_in[11]};
    const float* c_b1[2]  = {(const float*)d_in[4],  (const float*)d_in[12]};
    const float* c_g1[2]  = {(const float*)d_in[5],  (const float*)d_in[13]};
    const float* c_be1[2] = {(const float*)d_in[6],  (const float*)d_in[14]};
    const float* c_w2[2]  = {(const float*)d_in[7],  (const float*)d_in[15]};
    const float* c_b2[2]  = {(const float*)d_in[8],  (const float*)d_in[16]};
    const float* bn_g[2]  = {(const float*)d_in[9],  (const float*)d_in[17]};
    const float* bn_b[2]  = {(const float*)d_in[10], (const float*)d_in[18]};
    const float* lw[3]    = {(const float*)d_in[19], (const float*)d_in[21], (const float*)d_in[23]};
    const float* lb[3]    = {(const float*)d_in[20], (const float*)d_in[22], (const float*)d_in[24]};

    float* out = (float*)d_out;
    const size_t nh1 = (size_t)(N + 1) * 64;   // all node buffers get +1 pad row
    const int PG = (N + 127) / 128;   // gemm grid

    // workspace layout
    bf16*  zb    = (bf16*)d_ws;                // nh1 (L0 t/y buffer; row N = NaN unused by MODE1 mask)
    bf16*  wb    = zb + nh1;                   // nh1 (L1 t/y buffer)
    bf16*  xb    = wb + nh1;                   // nh1 (x cast, row N = 0)
    float* gs    = (float*)(xb + nh1);         // 4 x 128 stat slots (zeroed by initcast)
    int*   rowptr = (int*)(gs + 512);          // N
    int*   rowend = rowptr + N;                // N
    int*   adj    = rowend + N;                // NB*PCAP (8-padded rows)
    int*   tmp    = adj + (size_t)NB * PCAP;   // NB*CAP
    int*   bcur   = tmp + (size_t)NB * CAP;    // NB

    float* gs1 = gs;        // stats of t0 (L0 gemm1 out)
    float* gs2 = gs + 128;  // stats of y0 (L0 gemm2 out) -> act_A
    float* gs3 = gs + 256;  // stats of t1
    float* gs4 = gs + 384;  // stats of y1 -> act_B

    const float invN = 1.0f / (float)N;
    const int binGrid  = (E + CHUNK - 1) / CHUNK;
    const int aggGrid  = (N + 15) / 16;
    const int n4       = N * 16;               // cast region in 4-elem chunks
    const int total4   = (N + 1) * 16;         // + pad row
    const int ewGrid   = (total4 + 255) / 256;

    // ---- init+cast, CSR build (fixed-stride buckets, 8-padded rows) ----
    initcast_k<<<ewGrid, 256, 0, stream>>>(x, xb, zb, n4, total4, bcur, NB, gs);
    binscatter_k<<<binGrid, 256, 0, stream>>>(src, dst, bcur, tmp, E, NB);
    csr_k<<<NB, 256, 0, stream>>>(bcur, tmp, rowptr, rowend, adj, N);

    // ---- layer 0 ----
    aggregate_k<0><<<aggGrid, 256, 0, stream>>>(xb, rowptr, rowend, adj, zb, N,
                                                nullptr, nullptr, nullptr, 0.f);
    gemm64_k<0><<<PG, 256, 0, stream>>>(zb, nullptr, nullptr, nullptr, 0.f,
                                        c_w1[0], c_b1[0], zb, gs1, N);
    gemm64_k<1><<<PG, 256, 0, stream>>>(zb, gs1, c_g1[0], c_be1[0], invN,
                                        c_w2[0], c_b2[0], zb, gs2, N);

    // ---- layer 1 (h1 = relu(affine(y0)) fused into aggregate) ----
    aggregate_k<1><<<aggGrid, 256, 0, stream>>>(zb, rowptr, rowend, adj, wb, N,
                                                gs2, bn_g[0], bn_b[0], invN);
    gemm64_k<0><<<PG, 256, 0, stream>>>(wb, nullptr, nullptr, nullptr, 0.f,
                                        c_w1[1], c_b1[1], wb, gs3, N);
    gemm64_k<1><<<PG, 256, 0, stream>>>(wb, gs3, c_g1[1], c_be1[1], invN,
                                        c_w2[1], c_b2[1], wb, gs4, N);

    // ---- pooled readout (h1/h2 affine+relu fused) ----
    pool_readout_k<<<G, 256, 0, stream>>>(xb, zb, wb, batch,
                                          gs2, bn_g[0], bn_b[0],
                                          gs4, bn_g[1], bn_b[1], invN,
                                          lw[0], lb[0], lw[1], lb[1], lw[2], lb[2],
                                          out, N);
}